// Round 8
// baseline (208.625 us; speedup 1.0000x reference)
//
#include <hip/hip_runtime.h>
#include <stdint.h>

// Problem constants: B=4, T=2048, C=512, H=8, D=64
typedef __attribute__((ext_vector_type(8))) __bf16 bf16x8;
typedef __attribute__((ext_vector_type(4))) __bf16 bf16x4;
typedef __attribute__((ext_vector_type(2))) __bf16 bf16x2;
typedef __attribute__((ext_vector_type(4))) float f32x4;
typedef __attribute__((ext_vector_type(16))) float f32x16;
typedef __attribute__((ext_vector_type(4))) unsigned u32x4;
typedef __attribute__((ext_vector_type(2))) int i32x2;

__device__ __forceinline__ unsigned short f2bf(float f) {
  unsigned u = __float_as_uint(f);
  u += 0x7FFFu + ((u >> 16) & 1u);   // round-to-nearest-even
  return (unsigned short)(u >> 16);
}

__device__ __forceinline__ float exp2fast(float x) {
#if __has_builtin(__builtin_amdgcn_exp2f)
  return __builtin_amdgcn_exp2f(x);
#else
  return __expf(x * 0.6931471805599453f);
#endif
}

__device__ __forceinline__ void pl32swap(unsigned &a, unsigned &b) {
#if __has_builtin(__builtin_amdgcn_permlane32_swap)
  i32x2 r = __builtin_amdgcn_permlane32_swap((int)a, (int)b, false, false);
  a = (unsigned)r[0]; b = (unsigned)r[1];
#else
  asm volatile("v_permlane32_swap_b32 %0, %1" : "+v"(a), "+v"(b));
#endif
}

// rows r, r+8, r+16, r+24 get distinct octets (2-way max aliasing anywhere)
__device__ __forceinline__ int swz8(int r) { return (r & 7) ^ ((r >> 3) & 3); }

__device__ __forceinline__ void gload16(const unsigned short* src, unsigned short* ldsdst) {
  __builtin_amdgcn_global_load_lds(
      (const __attribute__((address_space(1))) unsigned int*)src,
      (__attribute__((address_space(3))) unsigned int*)ldsdst, 16, 0, 0);
}

// Stage 8 rows x 64 bf16 (128B/row) into LDS tile (linear dest), with the
// global-source octet XOR-swizzled by swz8(row) so swizzled reads are
// bank-conflict-free (G21: swizzle source+read, dest stays linear).
__device__ __forceinline__ void stage8(const unsigned short* gbase, long long strideElems,
                                       unsigned short* ldsTile, int rowBase) {
  const int lane = threadIdx.x & 63;
  const int r = rowBase + (lane >> 3);
  const int oct = (lane & 7) ^ swz8(r);
  gload16(gbase + (long long)r * strideElems + oct * 8, ldsTile + rowBase * 64);
}

// ---------------- merged prep kernel ----------------

__global__ __launch_bounds__(256) void prep(const float* __restrict__ x,
                                            unsigned short* __restrict__ xb,
                                            const float* __restrict__ wq,
                                            unsigned short* __restrict__ wqt,
                                            const float* __restrict__ wp,
                                            unsigned short* __restrict__ wpt,
                                            const int* __restrict__ adj,
                                            unsigned long long* __restrict__ mb) {
  int blk = blockIdx.x;
  if (blk < 16384) {
    int tid = blk * 256 + threadIdx.x;
    int4 v = ((const int4*)adj)[tid];
    unsigned n = (v.x != 0 ? 1u : 0u) | (v.y != 0 ? 2u : 0u) |
                 (v.z != 0 ? 4u : 0u) | (v.w != 0 ? 8u : 0u);
    unsigned long long part = (unsigned long long)n << ((threadIdx.x & 15) * 4);
    part |= __shfl_xor(part, 1);
    part |= __shfl_xor(part, 2);
    part |= __shfl_xor(part, 4);
    part |= __shfl_xor(part, 8);
    if ((threadIdx.x & 15) == 0) mb[tid >> 4] = part;
    return;
  }
  blk -= 16384;
  if (blk < 4096) {
    int i = (blk * 256 + threadIdx.x) * 4;
    float4 v = *(const float4*)(x + i);
    ushort4 o;
    o.x = f2bf(v.x); o.y = f2bf(v.y); o.z = f2bf(v.z); o.w = f2bf(v.w);
    *(ushort4*)(xb + i) = o;
    return;
  }
  blk -= 4096;
  const float* w; unsigned short* wt; int N; int bx, by;
  if (blk < 768) { w = wq; wt = wqt; N = 1536; bx = blk & 15; by = blk >> 4; }
  else { blk -= 768; w = wp; wt = wpt; N = 512; bx = blk & 15; by = blk >> 4; }
  __shared__ float tile[32][33];
  int k0 = bx * 32, n0 = by * 32;
  int tx = threadIdx.x & 31, ty = threadIdx.x >> 5;
#pragma unroll
  for (int i = 0; i < 4; i++)
    tile[ty + i * 8][tx] = w[(long long)(k0 + ty + i * 8) * N + n0 + tx];
  __syncthreads();
#pragma unroll
  for (int i = 0; i < 4; i++)
    wt[(long long)(n0 + ty + i * 8) * 512 + k0 + tx] = f2bf(tile[tx][ty + i * 8]);
}

// ---------------- GEMM core: C[128x128] = A[M,512] * Wt[N,512]^T ----------------
// m97 structure: single-buffered 32KB LDS (5 blocks/CU), per K-step:
// barrier; stage; vmcnt(0); barrier; compute.

__device__ __forceinline__ void gemm_core(const unsigned short* __restrict__ A,
                                          const unsigned short* __restrict__ Wt,
                                          unsigned short* Al, unsigned short* Bl,
                                          int m0, int n0, f32x4 acc[4][4]) {
  const int lane = threadIdx.x & 63;
  const int wid = threadIdx.x >> 6;
  const int c = lane & 15, g = lane >> 4;
  const int wm = wid >> 1, wn = wid & 1;
  const unsigned short* Ab = A + (long long)m0 * 512;
  const unsigned short* Bb = Wt + (long long)n0 * 512;

  for (int k0 = 0; k0 < 512; k0 += 64) {
    __syncthreads();
#pragma unroll
    for (int i = 0; i < 4; i++) stage8(Ab + k0, 512, Al, wid * 32 + i * 8);
#pragma unroll
    for (int i = 0; i < 4; i++) stage8(Bb + k0, 512, Bl, wid * 32 + i * 8);
    asm volatile("s_waitcnt vmcnt(0)" ::: "memory");
    __syncthreads();
#pragma unroll
    for (int kk = 0; kk < 2; kk++) {
      bf16x8 af[4], bfr[4];
#pragma unroll
      for (int mi = 0; mi < 4; mi++) {
        int row = wm * 64 + mi * 16 + c;
        af[mi] = *(const bf16x8*)&Al[row * 64 + (((kk << 2) | g) ^ swz8(row)) * 8];
      }
#pragma unroll
      for (int ni = 0; ni < 4; ni++) {
        int row = wn * 64 + ni * 16 + c;
        bfr[ni] = *(const bf16x8*)&Bl[row * 64 + (((kk << 2) | g) ^ swz8(row)) * 8];
      }
#pragma unroll
      for (int mi = 0; mi < 4; mi++)
#pragma unroll
        for (int ni = 0; ni < 4; ni++)
          acc[mi][ni] = __builtin_amdgcn_mfma_f32_16x16x32_bf16(af[mi], bfr[ni], acc[mi][ni], 0, 0, 0);
    }
  }
}

__global__ __launch_bounds__(256) void gemm_qkv(const unsigned short* __restrict__ xb,
                                                const unsigned short* __restrict__ wqt,
                                                const float* __restrict__ bqkv,
                                                unsigned short* __restrict__ qb,
                                                unsigned short* __restrict__ kb,
                                                unsigned short* __restrict__ vtb) {
  __shared__ __align__(16) unsigned short Al[128 * 64];
  __shared__ __align__(16) unsigned short Bl[128 * 64];
  f32x4 acc[4][4] = {};
  int m0 = blockIdx.x * 128, n0 = blockIdx.y * 128;
  gemm_core(xb, wqt, Al, Bl, m0, n0, acc);
  const int lane = threadIdx.x & 63;
  const int wid = threadIdx.x >> 6;
  const int c = lane & 15, g = lane >> 4;
  const int wm = wid >> 1, wn = wid & 1;
#pragma unroll
  for (int ni = 0; ni < 4; ni++) {
    int n = n0 + wn * 64 + ni * 16 + c;
    float bv = bqkv[n];
    int which = n >> 9;
    int h = (n & 511) >> 6, d = n & 63;
#pragma unroll
    for (int mi = 0; mi < 4; mi++) {
      int mbase = m0 + wm * 64 + mi * 16 + g * 4;   // 4 consecutive t, same batch
      int b = mbase >> 11, t0 = mbase & 2047;
      int bh = b * 8 + h;
      if (which == 2) {
        // V transposed [bh][d][t]: 4 consecutive t -> one 8B store
        ushort4 o;
        o.x = f2bf(acc[mi][ni][0] + bv); o.y = f2bf(acc[mi][ni][1] + bv);
        o.z = f2bf(acc[mi][ni][2] + bv); o.w = f2bf(acc[mi][ni][3] + bv);
        *(ushort4*)&vtb[((long long)bh * 64 + d) * 2048 + t0] = o;
      } else if (which == 0) {
#pragma unroll
        for (int j = 0; j < 4; j++)
          qb[(bh * 2048 + t0 + j) * 64 + d] = f2bf((acc[mi][ni][j] + bv) * 0.18033688011112042f);
      } else {
#pragma unroll
        for (int j = 0; j < 4; j++)
          kb[(bh * 2048 + t0 + j) * 64 + d] = f2bf(acc[mi][ni][j] + bv);
      }
    }
  }
}

__global__ __launch_bounds__(256) void gemm_proj(const unsigned short* __restrict__ yb,
                                                 const unsigned short* __restrict__ wpt,
                                                 const float* __restrict__ bproj,
                                                 float* __restrict__ out) {
  __shared__ __align__(16) unsigned short Al[128 * 64];
  __shared__ __align__(16) unsigned short Bl[128 * 64];
  f32x4 acc[4][4] = {};
  int m0 = blockIdx.x * 128, n0 = blockIdx.y * 128;
  gemm_core(yb, wpt, Al, Bl, m0, n0, acc);
  const int lane = threadIdx.x & 63;
  const int wid = threadIdx.x >> 6;
  const int c = lane & 15, g = lane >> 4;
  const int wm = wid >> 1, wn = wid & 1;
#pragma unroll
  for (int ni = 0; ni < 4; ni++) {
    int n = n0 + wn * 64 + ni * 16 + c;
    float bv = bproj[n];
#pragma unroll
    for (int mi = 0; mi < 4; mi++) {
      int mbase = m0 + wm * 64 + mi * 16 + g * 4;
#pragma unroll
      for (int j = 0; j < 4; j++)
        out[(long long)(mbase + j) * 512 + n] = acc[mi][ni][j] + bv;
    }
  }
}

// ---------------- flash attention: barrier-free, direct L2 reads, in-block kv-split ----
// Grid: 2048 blocks x 128 threads. bh = bid&31 (XCD-colocated -> K/V L2-resident),
// qblock = bid>>5 (32 q-rows). Wave w of the block handles kv half [w*1024, +1024)
// for the SAME 32 q-rows (no-max exp2 softmax => partials add exactly); one LDS
// combine + single barrier at the end. No K/V staging: fragments are read
// directly from global (contiguous 16B per lane; L1/L2-served). No per-tile
// syncs at all -> waves free-run; occupancy 16 waves/CU (VGPR<=128).
__global__ __launch_bounds__(128, 4) void attn(const unsigned short* __restrict__ qb,
                                               const unsigned short* __restrict__ kb,
                                               const unsigned short* __restrict__ vtb,
                                               const unsigned long long* __restrict__ mbits,
                                               unsigned short* __restrict__ yb) {
  __shared__ __align__(16) float lut4[16][4];     // nibble -> f32x4 seed (0 / -1e30)
  __shared__ __align__(16) float xch[2][64][17];  // cross-wave O-partial exchange
  __shared__ float xl[2][64];                     // cross-wave l-partial exchange
  const int lane = threadIdx.x & 63;
  const int w = threadIdx.x >> 6;          // wave 0/1 = kv half
  const int l31 = lane & 31, h5 = lane >> 5;
  const int bid = blockIdx.x;
  const int bh = bid & 31;                 // xcd = bid%8 = bh%8 -> K/V L2-resident
  const int q0 = (bid >> 5) * 32;
  const int b = bh >> 3, h = bh & 7;
  const int qglob = q0 + l31;
  const int kvbase = w * 1024;

  if (threadIdx.x < 16) {
    int n = threadIdx.x;
#pragma unroll
    for (int j = 0; j < 4; j++) lut4[n][j] = ((n >> j) & 1) ? 0.0f : -1e30f;
  }
  __syncthreads();

  const unsigned short* qptr = qb + ((long long)bh * 2048 + qglob) * 64;
  bf16x8 qf[4];
#pragma unroll
  for (int cc = 0; cc < 4; cc++) qf[cc] = *(const bf16x8*)(qptr + cc * 16 + h5 * 8);

  const unsigned long long* mrow = mbits + ((long long)b * 2048 + qglob) * 32 + w * 16;
  // this wave's kv-half bases; K rows = kv, V^T rows = d
  const unsigned short* kh = kb + ((long long)bh * 2048 + kvbase) * 64;
  const unsigned short* vh = vtb + (long long)bh * 64 * 2048 + kvbase;

  f32x16 accO0 = {0,0,0,0, 0,0,0,0, 0,0,0,0, 0,0,0,0};
  f32x16 accO1 = {0,0,0,0, 0,0,0,0, 0,0,0,0, 0,0,0,0};
  float lrun = 0.0f;
  unsigned long long mw = mrow[0];

  for (int t = 0; t < 16; ++t) {
    // ---- K fragments direct from global (L1/L2) ----
    const unsigned short* Krow = kh + ((long long)t * 64 + l31) * 64 + h5 * 8;
    bf16x8 kf0[4], kf1[4];
#pragma unroll
    for (int cc = 0; cc < 4; cc++) {
      kf0[cc] = *(const bf16x8*)(Krow + cc * 16);
      kf1[cc] = *(const bf16x8*)(Krow + 32 * 64 + cc * 16);
    }

    // ---- seed S^T accumulators from the nibble LUT ----
    // C reg r of tile ot: kv = ot*32 + (r&3) + 8*(r>>2) + 4*h5
    unsigned lo = (unsigned)mw, hi = (unsigned)(mw >> 32);
    f32x16 st0, st1;
#pragma unroll
    for (int j = 0; j < 4; j++) {
      f32x4 s0 = *(const f32x4*)lut4[(lo >> (8 * j + 4 * h5)) & 0xF];
      f32x4 s1 = *(const f32x4*)lut4[(hi >> (8 * j + 4 * h5)) & 0xF];
#pragma unroll
      for (int i = 0; i < 4; i++) { st0[4 * j + i] = s0[i]; st1[4 * j + i] = s1[i]; }
    }
    if (t < 15) mw = mrow[t + 1];

    // ---- S^T = K * Q^T ----
    __builtin_amdgcn_s_setprio(1);
#pragma unroll
    for (int cc = 0; cc < 4; cc++) {
      st0 = __builtin_amdgcn_mfma_f32_32x32x16_bf16(kf0[cc], qf[cc], st0, 0, 0, 0);
      st1 = __builtin_amdgcn_mfma_f32_32x32x16_bf16(kf1[cc], qf[cc], st1, 0, 0, 0);
    }
    __builtin_amdgcn_s_setprio(0);

    // ---- V fragments issued now; latency hides under the exp2 chain ----
    const unsigned short* Vrow = vh + (long long)l31 * 2048 + t * 64 + h5 * 8;
    bf16x8 vf0[4], vf1[4];
#pragma unroll
    for (int cc = 0; cc < 4; cc++) {
      vf0[cc] = *(const bf16x8*)(Vrow + cc * 16);
      vf1[cc] = *(const bf16x8*)(Vrow + 32 * 2048 + cc * 16);
    }

    // ---- exp2 softmax (masked entries hit exp2(-1e30) = 0), pack bf16 ----
    unsigned pd[2][8];
    float lsum = 0.0f;
#pragma unroll
    for (int m = 0; m < 8; m++) {
      const int r0 = 2 * m, r1 = 2 * m + 1;
      float p0 = exp2fast(st0[r0]);
      float p1 = exp2fast(st0[r1]);
      float p2 = exp2fast(st1[r0]);
      float p3 = exp2fast(st1[r1]);
      lsum += (p0 + p1) + (p2 + p3);
      bf16x2 v0 = {(__bf16)p0, (__bf16)p1};
      bf16x2 v1 = {(__bf16)p2, (__bf16)p3};
      pd[0][m] = __builtin_bit_cast(unsigned, v0);
      pd[1][m] = __builtin_bit_cast(unsigned, v1);
    }
    lrun += lsum;

    // ---- PV B-fragments: l <-> l+32 dword exchange ----
#pragma unroll
    for (int ot = 0; ot < 2; ot++)
#pragma unroll
      for (int hc = 0; hc < 2; hc++) {
        pl32swap(pd[ot][4 * hc + 0], pd[ot][4 * hc + 2]);
        pl32swap(pd[ot][4 * hc + 1], pd[ot][4 * hc + 3]);
      }

    // ---- O^T += V^T * P^T ----
    __builtin_amdgcn_s_setprio(1);
#pragma unroll
    for (int cc = 0; cc < 4; cc++) {
      u32x4 pu = {pd[cc >> 1][4 * (cc & 1) + 0], pd[cc >> 1][4 * (cc & 1) + 1],
                  pd[cc >> 1][4 * (cc & 1) + 2], pd[cc >> 1][4 * (cc & 1) + 3]};
      bf16x8 pf = __builtin_bit_cast(bf16x8, pu);
      accO0 = __builtin_amdgcn_mfma_f32_32x32x16_bf16(vf0[cc], pf, accO0, 0, 0, 0);
      accO1 = __builtin_amdgcn_mfma_f32_32x32x16_bf16(vf1[cc], pf, accO1, 0, 0, 0);
    }
    __builtin_amdgcn_s_setprio(0);
  }

  // ---- in-block kv-half combine via LDS (one barrier total) ----
  // wave w keeps half w's d-range: wave0 -> accO0 (d<32), wave1 -> accO1 (d>=32);
  // it donates the other half through LDS.
  {
    float* dst = &xch[w][lane][0];
    f32x16 give = w ? accO0 : accO1;
#pragma unroll
    for (int i = 0; i < 16; i++) dst[i] = give[i];
    xl[w][lane] = lrun;
  }
  __syncthreads();
  {
    const float* src = &xch[w ^ 1][lane][0];
    f32x16 keep = w ? accO1 : accO0;
#pragma unroll
    for (int i = 0; i < 16; i++) keep[i] += src[i];
    float ltot = (xl[0][l31] + xl[0][l31 + 32]) + (xl[1][l31] + xl[1][l31 + 32]);
    float linv = 1.0f / ltot;
    unsigned short* yrow = yb + ((long long)(b * 2048 + qglob)) * 512 + h * 64 + w * 32;
#pragma unroll
    for (int m = 0; m < 4; m++) {
      int d0 = 8 * m + 4 * h5;
      bf16x4 o = {(__bf16)(keep[4 * m + 0] * linv), (__bf16)(keep[4 * m + 1] * linv),
                  (__bf16)(keep[4 * m + 2] * linv), (__bf16)(keep[4 * m + 3] * linv)};
      *(bf16x4*)&yrow[d0] = o;
    }
  }
}

// ---------------- launcher ----------------

extern "C" void kernel_launch(void* const* d_in, const int* in_sizes, int n_in,
                              void* d_out, int out_size, void* d_ws, size_t ws_size,
                              hipStream_t stream) {
  const float* x      = (const float*)d_in[0];
  const int*   adj    = (const int*)d_in[1];
  const float* w_qkv  = (const float*)d_in[2];
  const float* b_qkv  = (const float*)d_in[3];
  const float* w_proj = (const float*)d_in[4];
  const float* b_proj = (const float*)d_in[5];
  float* out = (float*)d_out;

  char* ws = (char*)d_ws;
  unsigned short* xb  = (unsigned short*)(ws);              // 8.4MB  (reused as yb)
  unsigned short* qb  = (unsigned short*)(ws + 8388608);    // 8.4MB
  unsigned short* kbf = (unsigned short*)(ws + 16777216);   // 8.4MB
  unsigned short* vtb = (unsigned short*)(ws + 25165824);   // 8.4MB
  unsigned short* wqt = (unsigned short*)(ws + 33554432);   // 1.57MB
  unsigned short* wpt = (unsigned short*)(ws + 35127296);   // 0.52MB
  unsigned long long* mb = (unsigned long long*)(ws + 35651584); // 2MB  (end 37.75MB)
  unsigned short* yb = xb;  // x is dead after gemm_qkv

  prep<<<dim3(21504), dim3(256), 0, stream>>>(x, xb, w_qkv, wqt, w_proj, wpt, adj, mb);
  gemm_qkv<<<dim3(64, 12), dim3(256), 0, stream>>>(xb, wqt, b_qkv, qb, kbf, vtb);
  attn<<<dim3(2048), dim3(128), 0, stream>>>(qb, kbf, vtb, mb, yb);
  gemm_proj<<<dim3(64, 4), dim3(256), 0, stream>>>(yb, wpt, b_proj, out);
}

// Round 9
// 115.207 us; speedup vs baseline: 1.8109x; 1.8109x over previous
//
#include <hip/hip_runtime.h>
#include <stdint.h>

// Problem constants: B=4, T=2048, C=512, H=8, D=64
typedef __attribute__((ext_vector_type(8))) __bf16 bf16x8;
typedef __attribute__((ext_vector_type(4))) __bf16 bf16x4;
typedef __attribute__((ext_vector_type(2))) __bf16 bf16x2;
typedef __attribute__((ext_vector_type(4))) float f32x4;
typedef __attribute__((ext_vector_type(16))) float f32x16;
typedef __attribute__((ext_vector_type(4))) unsigned u32x4;
typedef __attribute__((ext_vector_type(2))) int i32x2;

__device__ __forceinline__ unsigned short f2bf(float f) {
  unsigned u = __float_as_uint(f);
  u += 0x7FFFu + ((u >> 16) & 1u);   // round-to-nearest-even
  return (unsigned short)(u >> 16);
}

__device__ __forceinline__ float exp2fast(float x) {
#if __has_builtin(__builtin_amdgcn_exp2f)
  return __builtin_amdgcn_exp2f(x);
#else
  return __expf(x * 0.6931471805599453f);
#endif
}

__device__ __forceinline__ void pl32swap(unsigned &a, unsigned &b) {
#if __has_builtin(__builtin_amdgcn_permlane32_swap)
  i32x2 r = __builtin_amdgcn_permlane32_swap((int)a, (int)b, false, false);
  a = (unsigned)r[0]; b = (unsigned)r[1];
#else
  asm volatile("v_permlane32_swap_b32 %0, %1" : "+v"(a), "+v"(b));
#endif
}

// rows r, r+8, r+16, r+24 get distinct octets (2-way max aliasing anywhere)
__device__ __forceinline__ int swz8(int r) { return (r & 7) ^ ((r >> 3) & 3); }

__device__ __forceinline__ void gload16(const unsigned short* src, unsigned short* ldsdst) {
  __builtin_amdgcn_global_load_lds(
      (const __attribute__((address_space(1))) unsigned int*)src,
      (__attribute__((address_space(3))) unsigned int*)ldsdst, 16, 0, 0);
}

// Stage 8 rows x 64 bf16 (128B/row) into LDS tile (linear dest), with the
// global-source octet XOR-swizzled by swz8(row) so swizzled reads are
// bank-conflict-free (G21: swizzle source+read, dest stays linear).
__device__ __forceinline__ void stage8(const unsigned short* gbase, long long strideElems,
                                       unsigned short* ldsTile, int rowBase) {
  const int lane = threadIdx.x & 63;
  const int r = rowBase + (lane >> 3);
  const int oct = (lane & 7) ^ swz8(r);
  gload16(gbase + (long long)r * strideElems + oct * 8, ldsTile + rowBase * 64);
}

// ---------------- merged prep kernel ----------------

__global__ __launch_bounds__(256) void prep(const float* __restrict__ x,
                                            unsigned short* __restrict__ xb,
                                            const float* __restrict__ wq,
                                            unsigned short* __restrict__ wqt,
                                            const float* __restrict__ wp,
                                            unsigned short* __restrict__ wpt,
                                            const int* __restrict__ adj,
                                            unsigned long long* __restrict__ mb) {
  int blk = blockIdx.x;
  if (blk < 16384) {
    int tid = blk * 256 + threadIdx.x;
    int4 v = ((const int4*)adj)[tid];
    unsigned n = (v.x != 0 ? 1u : 0u) | (v.y != 0 ? 2u : 0u) |
                 (v.z != 0 ? 4u : 0u) | (v.w != 0 ? 8u : 0u);
    unsigned long long part = (unsigned long long)n << ((threadIdx.x & 15) * 4);
    part |= __shfl_xor(part, 1);
    part |= __shfl_xor(part, 2);
    part |= __shfl_xor(part, 4);
    part |= __shfl_xor(part, 8);
    if ((threadIdx.x & 15) == 0) mb[tid >> 4] = part;
    return;
  }
  blk -= 16384;
  if (blk < 4096) {
    int i = (blk * 256 + threadIdx.x) * 4;
    float4 v = *(const float4*)(x + i);
    ushort4 o;
    o.x = f2bf(v.x); o.y = f2bf(v.y); o.z = f2bf(v.z); o.w = f2bf(v.w);
    *(ushort4*)(xb + i) = o;
    return;
  }
  blk -= 4096;
  const float* w; unsigned short* wt; int N; int bx, by;
  if (blk < 768) { w = wq; wt = wqt; N = 1536; bx = blk & 15; by = blk >> 4; }
  else { blk -= 768; w = wp; wt = wpt; N = 512; bx = blk & 15; by = blk >> 4; }
  __shared__ float tile[32][33];
  int k0 = bx * 32, n0 = by * 32;
  int tx = threadIdx.x & 31, ty = threadIdx.x >> 5;
#pragma unroll
  for (int i = 0; i < 4; i++)
    tile[ty + i * 8][tx] = w[(long long)(k0 + ty + i * 8) * N + n0 + tx];
  __syncthreads();
#pragma unroll
  for (int i = 0; i < 4; i++)
    wt[(long long)(n0 + ty + i * 8) * 512 + k0 + tx] = f2bf(tile[tx][ty + i * 8]);
}

// ---------------- GEMM core: C[128x128] = A[M,512] * Wt[N,512]^T ----------------
// m97 structure: single-buffered 32KB LDS, per K-step:
// barrier; stage; vmcnt(0); barrier; compute.

__device__ __forceinline__ void gemm_core(const unsigned short* __restrict__ A,
                                          const unsigned short* __restrict__ Wt,
                                          unsigned short* Al, unsigned short* Bl,
                                          int m0, int n0, f32x4 acc[4][4]) {
  const int lane = threadIdx.x & 63;
  const int wid = threadIdx.x >> 6;
  const int c = lane & 15, g = lane >> 4;
  const int wm = wid >> 1, wn = wid & 1;
  const unsigned short* Ab = A + (long long)m0 * 512;
  const unsigned short* Bb = Wt + (long long)n0 * 512;

  for (int k0 = 0; k0 < 512; k0 += 64) {
    __syncthreads();
#pragma unroll
    for (int i = 0; i < 4; i++) stage8(Ab + k0, 512, Al, wid * 32 + i * 8);
#pragma unroll
    for (int i = 0; i < 4; i++) stage8(Bb + k0, 512, Bl, wid * 32 + i * 8);
    asm volatile("s_waitcnt vmcnt(0)" ::: "memory");
    __syncthreads();
#pragma unroll
    for (int kk = 0; kk < 2; kk++) {
      bf16x8 af[4], bfr[4];
#pragma unroll
      for (int mi = 0; mi < 4; mi++) {
        int row = wm * 64 + mi * 16 + c;
        af[mi] = *(const bf16x8*)&Al[row * 64 + (((kk << 2) | g) ^ swz8(row)) * 8];
      }
#pragma unroll
      for (int ni = 0; ni < 4; ni++) {
        int row = wn * 64 + ni * 16 + c;
        bfr[ni] = *(const bf16x8*)&Bl[row * 64 + (((kk << 2) | g) ^ swz8(row)) * 8];
      }
#pragma unroll
      for (int mi = 0; mi < 4; mi++)
#pragma unroll
        for (int ni = 0; ni < 4; ni++)
          acc[mi][ni] = __builtin_amdgcn_mfma_f32_16x16x32_bf16(af[mi], bfr[ni], acc[mi][ni], 0, 0, 0);
    }
  }
}

__global__ __launch_bounds__(256) void gemm_qkv(const unsigned short* __restrict__ xb,
                                                const unsigned short* __restrict__ wqt,
                                                const float* __restrict__ bqkv,
                                                unsigned short* __restrict__ qb,
                                                unsigned short* __restrict__ kb,
                                                unsigned short* __restrict__ vtb) {
  __shared__ __align__(16) unsigned short Al[128 * 64];
  __shared__ __align__(16) unsigned short Bl[128 * 64];
  f32x4 acc[4][4] = {};
  int m0 = blockIdx.x * 128, n0 = blockIdx.y * 128;
  gemm_core(xb, wqt, Al, Bl, m0, n0, acc);
  const int lane = threadIdx.x & 63;
  const int wid = threadIdx.x >> 6;
  const int c = lane & 15, g = lane >> 4;
  const int wm = wid >> 1, wn = wid & 1;
#pragma unroll
  for (int ni = 0; ni < 4; ni++) {
    int n = n0 + wn * 64 + ni * 16 + c;
    float bv = bqkv[n];
    int which = n >> 9;
    int h = (n & 511) >> 6, d = n & 63;
#pragma unroll
    for (int mi = 0; mi < 4; mi++) {
      int mbase = m0 + wm * 64 + mi * 16 + g * 4;   // 4 consecutive t, same batch
      int b = mbase >> 11, t0 = mbase & 2047;
      int bh = b * 8 + h;
      if (which == 2) {
        // V transposed [bh][d][t]: 4 consecutive t -> one 8B store
        ushort4 o;
        o.x = f2bf(acc[mi][ni][0] + bv); o.y = f2bf(acc[mi][ni][1] + bv);
        o.z = f2bf(acc[mi][ni][2] + bv); o.w = f2bf(acc[mi][ni][3] + bv);
        *(ushort4*)&vtb[((long long)bh * 64 + d) * 2048 + t0] = o;
      } else if (which == 0) {
#pragma unroll
        for (int j = 0; j < 4; j++)
          qb[(bh * 2048 + t0 + j) * 64 + d] = f2bf((acc[mi][ni][j] + bv) * 0.18033688011112042f);
      } else {
#pragma unroll
        for (int j = 0; j < 4; j++)
          kb[(bh * 2048 + t0 + j) * 64 + d] = f2bf(acc[mi][ni][j] + bv);
      }
    }
  }
}

__global__ __launch_bounds__(256) void gemm_proj(const unsigned short* __restrict__ yb,
                                                 const unsigned short* __restrict__ wpt,
                                                 const float* __restrict__ bproj,
                                                 float* __restrict__ out) {
  __shared__ __align__(16) unsigned short Al[128 * 64];
  __shared__ __align__(16) unsigned short Bl[128 * 64];
  f32x4 acc[4][4] = {};
  int m0 = blockIdx.x * 128, n0 = blockIdx.y * 128;
  gemm_core(yb, wpt, Al, Bl, m0, n0, acc);
  const int lane = threadIdx.x & 63;
  const int wid = threadIdx.x >> 6;
  const int c = lane & 15, g = lane >> 4;
  const int wm = wid >> 1, wn = wid & 1;
#pragma unroll
  for (int ni = 0; ni < 4; ni++) {
    int n = n0 + wn * 64 + ni * 16 + c;
    float bv = bproj[n];
#pragma unroll
    for (int mi = 0; mi < 4; mi++) {
      int mbase = m0 + wm * 64 + mi * 16 + g * 4;
#pragma unroll
      for (int j = 0; j < 4; j++)
        out[(long long)(mbase + j) * 512 + n] = acc[mi][ni][j] + bv;
    }
  }
}

// ---------------- flash attention: 4-wave shared staging, triple-buffer, counted vmcnt ----
// Grid: 512 blocks x 256 thr. bh = bid&31 (XCD-colocated K/V), qblock of 128 rows,
// wave w owns 32 q-rows. K/V staged to LDS cooperatively (4 waves, 4 gload16 +
// 1 mask load = exactly 5 VMEM per wave per tile). T3/T4: 3 LDS buffers, raw
// s_barrier + counted s_waitcnt vmcnt(5) per tile — never vmcnt(0) in the loop,
// so tile t+2's loads stay in flight across 2 barriers (~2 compute-tiles of
// latency cover). Overwrite of buf[(t+3)%3]=buf[t%3] is safe: its readers
// finished compute(t) before the barrier that precedes the write (lgkmcnt(0)
// fence before each barrier guarantees ds_reads completed).
__global__ __launch_bounds__(256) void attn(const unsigned short* __restrict__ qb,
                                            const unsigned short* __restrict__ kb,
                                            const unsigned short* __restrict__ vtb,
                                            const unsigned long long* __restrict__ mbits,
                                            unsigned short* __restrict__ yb) {
  __shared__ __align__(16) unsigned short Kl[3][64 * 64];
  __shared__ __align__(16) unsigned short Vl[3][64 * 64];
  __shared__ __align__(16) float lut4[16][4];   // nibble -> f32x4 seed (0 / -1e30)
  const int lane = threadIdx.x & 63;
  const int w = threadIdx.x >> 6;          // wave 0..3
  const int l31 = lane & 31, h5 = lane >> 5;
  const int sA = swz8(l31);                // swz8(l31+32) == swz8(l31)
  const int bid = blockIdx.x;
  const int bh = bid & 31;                 // xcd = bid%8 = bh%8 -> K/V L2-resident
  const int q0 = (bid >> 5) * 128;
  const int b = bh >> 3, h = bh & 7;
  const int qglob = q0 + w * 32 + l31;

  if (threadIdx.x < 16) {
    int n = threadIdx.x;
#pragma unroll
    for (int j = 0; j < 4; j++) lut4[n][j] = ((n >> j) & 1) ? 0.0f : -1e30f;
  }
  __syncthreads();

  const unsigned short* qptr = qb + ((long long)bh * 2048 + qglob) * 64;
  bf16x8 qf[4];
#pragma unroll
  for (int cc = 0; cc < 4; cc++) qf[cc] = *(const bf16x8*)(qptr + cc * 16 + h5 * 8);

  const unsigned long long* mrow = mbits + ((long long)b * 2048 + qglob) * 32;
  const unsigned short* kbase = kb + (long long)bh * 2048 * 64;
  const unsigned short* vbase = vtb + (long long)bh * 64 * 2048;

  f32x16 accO0 = {0,0,0,0, 0,0,0,0, 0,0,0,0, 0,0,0,0};
  f32x16 accO1 = {0,0,0,0, 0,0,0,0, 0,0,0,0, 0,0,0,0};
  float lrun = 0.0f;

  // stage tile kvt into buffer bi (4 gload16 per wave: 16 K rows + 16 V rows)
  auto STAGE = [&](int kvt, int bi) {
    long long kv0 = (long long)kvt * 64;
    stage8(kbase + kv0 * 64, 64, &Kl[bi][0], w * 16);
    stage8(kbase + kv0 * 64, 64, &Kl[bi][0], w * 16 + 8);
    stage8(vbase + kv0, 2048, &Vl[bi][0], w * 16);
    stage8(vbase + kv0, 2048, &Vl[bi][0], w * 16 + 8);
  };

  auto COMPUTE = [&](int bi, unsigned long long mwv) {
    const unsigned short* Kb = &Kl[bi][0];
    const unsigned short* Vb = &Vl[bi][0];
    // seed S^T accumulators from the nibble LUT
    // C reg r of tile ot: kv = ot*32 + (r&3) + 8*(r>>2) + 4*h5
    unsigned lo = (unsigned)mwv, hi = (unsigned)(mwv >> 32);
    f32x16 st0, st1;
#pragma unroll
    for (int j = 0; j < 4; j++) {
      f32x4 s0 = *(const f32x4*)lut4[(lo >> (8 * j + 4 * h5)) & 0xF];
      f32x4 s1 = *(const f32x4*)lut4[(hi >> (8 * j + 4 * h5)) & 0xF];
#pragma unroll
      for (int i = 0; i < 4; i++) { st0[4 * j + i] = s0[i]; st1[4 * j + i] = s1[i]; }
    }
    // S^T = K * Q^T
    __builtin_amdgcn_s_setprio(1);
#pragma unroll
    for (int cc = 0; cc < 4; cc++) {
      int u = ((cc * 2 + h5) ^ sA) * 8;
      bf16x8 kf0 = *(const bf16x8*)&Kb[l31 * 64 + u];
      bf16x8 kf1 = *(const bf16x8*)&Kb[(32 + l31) * 64 + u];
      st0 = __builtin_amdgcn_mfma_f32_32x32x16_bf16(kf0, qf[cc], st0, 0, 0, 0);
      st1 = __builtin_amdgcn_mfma_f32_32x32x16_bf16(kf1, qf[cc], st1, 0, 0, 0);
    }
    __builtin_amdgcn_s_setprio(0);
    // exp2 softmax (masked entries hit exp2(-1e30) = 0), pack bf16
    unsigned pd[2][8];
    float lsum = 0.0f;
#pragma unroll
    for (int m = 0; m < 8; m++) {
      const int r0 = 2 * m, r1 = 2 * m + 1;
      float p0 = exp2fast(st0[r0]);
      float p1 = exp2fast(st0[r1]);
      float p2 = exp2fast(st1[r0]);
      float p3 = exp2fast(st1[r1]);
      lsum += (p0 + p1) + (p2 + p3);
      bf16x2 v0 = {(__bf16)p0, (__bf16)p1};
      bf16x2 v1 = {(__bf16)p2, (__bf16)p3};
      pd[0][m] = __builtin_bit_cast(unsigned, v0);
      pd[1][m] = __builtin_bit_cast(unsigned, v1);
    }
    lrun += lsum;
    // PV B-fragments: l <-> l+32 dword exchange
#pragma unroll
    for (int ot = 0; ot < 2; ot++)
#pragma unroll
      for (int hc = 0; hc < 2; hc++) {
        pl32swap(pd[ot][4 * hc + 0], pd[ot][4 * hc + 2]);
        pl32swap(pd[ot][4 * hc + 1], pd[ot][4 * hc + 3]);
      }
    // O^T += V^T * P^T
    __builtin_amdgcn_s_setprio(1);
#pragma unroll
    for (int cc = 0; cc < 4; cc++) {
      u32x4 pu = {pd[cc >> 1][4 * (cc & 1) + 0], pd[cc >> 1][4 * (cc & 1) + 1],
                  pd[cc >> 1][4 * (cc & 1) + 2], pd[cc >> 1][4 * (cc & 1) + 3]};
      bf16x8 pf = __builtin_bit_cast(bf16x8, pu);
      int u = ((cc * 2 + h5) ^ sA) * 8;
      bf16x8 vf0 = *(const bf16x8*)&Vb[l31 * 64 + u];
      bf16x8 vf1 = *(const bf16x8*)&Vb[(32 + l31) * 64 + u];
      accO0 = __builtin_amdgcn_mfma_f32_32x32x16_bf16(vf0, pf, accO0, 0, 0, 0);
      accO1 = __builtin_amdgcn_mfma_f32_32x32x16_bf16(vf1, pf, accO1, 0, 0, 0);
    }
    __builtin_amdgcn_s_setprio(0);
  };

  // ---- prologue: tiles 0,1 in flight; exactly 5 VMEM per group, order pinned ----
  __builtin_amdgcn_sched_barrier(0);
  STAGE(0, 0);
  unsigned long long mw0 = mrow[0];
  __builtin_amdgcn_sched_barrier(0);
  STAGE(1, 1);
  unsigned long long mw1 = mrow[1];
  __builtin_amdgcn_sched_barrier(0);
  asm volatile("s_waitcnt vmcnt(5)" ::: "memory");   // tile-0 group landed
  __builtin_amdgcn_s_barrier();
  __builtin_amdgcn_sched_barrier(0);

  int rd = 0, wr = 2;
  unsigned long long mw2 = 0;
  for (int t = 0; t < 30; ++t) {
    STAGE(t + 2, wr);
    mw2 = mrow[t + 2];
    __builtin_amdgcn_sched_barrier(0);
    COMPUTE(rd, mw0);
    mw0 = mw1; mw1 = mw2;
    asm volatile("s_waitcnt lgkmcnt(0)" ::: "memory");
    asm volatile("s_waitcnt vmcnt(5)" ::: "memory"); // tile t+1 landed; t+2 in flight
    __builtin_amdgcn_s_barrier();
    __builtin_amdgcn_sched_barrier(0);
    rd = (rd == 2) ? 0 : rd + 1;
    wr = (wr == 2) ? 0 : wr + 1;
  }
  COMPUTE(rd, mw0);                                  // tile 30
  asm volatile("s_waitcnt lgkmcnt(0)" ::: "memory");
  asm volatile("s_waitcnt vmcnt(0)" ::: "memory");   // tile 31 landed
  __builtin_amdgcn_s_barrier();
  __builtin_amdgcn_sched_barrier(0);
  rd = (rd == 2) ? 0 : rd + 1;
  COMPUTE(rd, mw1);                                  // tile 31

  float linv = 1.0f / (lrun + __shfl_xor(lrun, 32));
  unsigned short* yrow = yb + ((long long)(b * 2048 + qglob)) * 512 + h * 64;
#pragma unroll
  for (int m = 0; m < 4; m++) {
    int d0 = 8 * m + 4 * h5;
    bf16x4 o0 = {(__bf16)(accO0[4 * m + 0] * linv), (__bf16)(accO0[4 * m + 1] * linv),
                 (__bf16)(accO0[4 * m + 2] * linv), (__bf16)(accO0[4 * m + 3] * linv)};
    bf16x4 o1 = {(__bf16)(accO1[4 * m + 0] * linv), (__bf16)(accO1[4 * m + 1] * linv),
                 (__bf16)(accO1[4 * m + 2] * linv), (__bf16)(accO1[4 * m + 3] * linv)};
    *(bf16x4*)&yrow[d0] = o0;
    *(bf16x4*)&yrow[32 + d0] = o1;
  }
}

// ---------------- launcher ----------------

extern "C" void kernel_launch(void* const* d_in, const int* in_sizes, int n_in,
                              void* d_out, int out_size, void* d_ws, size_t ws_size,
                              hipStream_t stream) {
  const float* x      = (const float*)d_in[0];
  const int*   adj    = (const int*)d_in[1];
  const float* w_qkv  = (const float*)d_in[2];
  const float* b_qkv  = (const float*)d_in[3];
  const float* w_proj = (const float*)d_in[4];
  const float* b_proj = (const float*)d_in[5];
  float* out = (float*)d_out;

  char* ws = (char*)d_ws;
  unsigned short* xb  = (unsigned short*)(ws);              // 8.4MB  (reused as yb)
  unsigned short* qb  = (unsigned short*)(ws + 8388608);    // 8.4MB
  unsigned short* kbf = (unsigned short*)(ws + 16777216);   // 8.4MB
  unsigned short* vtb = (unsigned short*)(ws + 25165824);   // 8.4MB
  unsigned short* wqt = (unsigned short*)(ws + 33554432);   // 1.57MB
  unsigned short* wpt = (unsigned short*)(ws + 35127296);   // 0.52MB
  unsigned long long* mb = (unsigned long long*)(ws + 35651584); // 2MB  (end 37.75MB)
  unsigned short* yb = xb;  // x is dead after gemm_qkv

  prep<<<dim3(21504), dim3(256), 0, stream>>>(x, xb, w_qkv, wqt, w_proj, wpt, adj, mb);
  gemm_qkv<<<dim3(64, 12), dim3(256), 0, stream>>>(xb, wqt, b_qkv, qb, kbf, vtb);
  attn<<<dim3(512), dim3(256), 0, stream>>>(qb, kbf, vtb, mb, yb);
  gemm_proj<<<dim3(64, 4), dim3(256), 0, stream>>>(yb, wpt, b_proj, out);
}

// Round 10
// 113.443 us; speedup vs baseline: 1.8390x; 1.0156x over previous
//
#include <hip/hip_runtime.h>
#include <stdint.h>

// Problem constants: B=4, T=2048, C=512, H=8, D=64
typedef __attribute__((ext_vector_type(8))) __bf16 bf16x8;
typedef __attribute__((ext_vector_type(4))) __bf16 bf16x4;
typedef __attribute__((ext_vector_type(2))) __bf16 bf16x2;
typedef __attribute__((ext_vector_type(4))) float f32x4;
typedef __attribute__((ext_vector_type(16))) float f32x16;
typedef __attribute__((ext_vector_type(4))) unsigned u32x4;
typedef __attribute__((ext_vector_type(2))) int i32x2;

__device__ __forceinline__ unsigned short f2bf(float f) {
  unsigned u = __float_as_uint(f);
  u += 0x7FFFu + ((u >> 16) & 1u);   // round-to-nearest-even
  return (unsigned short)(u >> 16);
}

__device__ __forceinline__ float exp2fast(float x) {
#if __has_builtin(__builtin_amdgcn_exp2f)
  return __builtin_amdgcn_exp2f(x);
#else
  return __expf(x * 0.6931471805599453f);
#endif
}

__device__ __forceinline__ void pl32swap(unsigned &a, unsigned &b) {
#if __has_builtin(__builtin_amdgcn_permlane32_swap)
  i32x2 r = __builtin_amdgcn_permlane32_swap((int)a, (int)b, false, false);
  a = (unsigned)r[0]; b = (unsigned)r[1];
#else
  asm volatile("v_permlane32_swap_b32 %0, %1" : "+v"(a), "+v"(b));
#endif
}

// rows r, r+8, r+16, r+24 get distinct octets (2-way max aliasing anywhere)
__device__ __forceinline__ int swz8(int r) { return (r & 7) ^ ((r >> 3) & 3); }

__device__ __forceinline__ void gload16(const unsigned short* src, unsigned short* ldsdst) {
  __builtin_amdgcn_global_load_lds(
      (const __attribute__((address_space(1))) unsigned int*)src,
      (__attribute__((address_space(3))) unsigned int*)ldsdst, 16, 0, 0);
}

// Stage 8 rows x 64 bf16 (128B/row) into LDS tile (linear dest), with the
// global-source octet XOR-swizzled by swz8(row) so swizzled reads are
// bank-conflict-free (G21: swizzle source+read, dest stays linear).
__device__ __forceinline__ void stage8(const unsigned short* gbase, long long strideElems,
                                       unsigned short* ldsTile, int rowBase) {
  const int lane = threadIdx.x & 63;
  const int r = rowBase + (lane >> 3);
  const int oct = (lane & 7) ^ swz8(r);
  gload16(gbase + (long long)r * strideElems + oct * 8, ldsTile + rowBase * 64);
}

// ---------------- merged prep kernel ----------------

__global__ __launch_bounds__(256) void prep(const float* __restrict__ x,
                                            unsigned short* __restrict__ xb,
                                            const float* __restrict__ wq,
                                            unsigned short* __restrict__ wqt,
                                            const float* __restrict__ wp,
                                            unsigned short* __restrict__ wpt,
                                            const int* __restrict__ adj,
                                            unsigned long long* __restrict__ mb) {
  int blk = blockIdx.x;
  if (blk < 16384) {
    int tid = blk * 256 + threadIdx.x;
    int4 v = ((const int4*)adj)[tid];
    unsigned n = (v.x != 0 ? 1u : 0u) | (v.y != 0 ? 2u : 0u) |
                 (v.z != 0 ? 4u : 0u) | (v.w != 0 ? 8u : 0u);
    unsigned long long part = (unsigned long long)n << ((threadIdx.x & 15) * 4);
    part |= __shfl_xor(part, 1);
    part |= __shfl_xor(part, 2);
    part |= __shfl_xor(part, 4);
    part |= __shfl_xor(part, 8);
    if ((threadIdx.x & 15) == 0) mb[tid >> 4] = part;
    return;
  }
  blk -= 16384;
  if (blk < 4096) {
    int i = (blk * 256 + threadIdx.x) * 4;
    float4 v = *(const float4*)(x + i);
    ushort4 o;
    o.x = f2bf(v.x); o.y = f2bf(v.y); o.z = f2bf(v.z); o.w = f2bf(v.w);
    *(ushort4*)(xb + i) = o;
    return;
  }
  blk -= 4096;
  const float* w; unsigned short* wt; int N; int bx, by;
  if (blk < 768) { w = wq; wt = wqt; N = 1536; bx = blk & 15; by = blk >> 4; }
  else { blk -= 768; w = wp; wt = wpt; N = 512; bx = blk & 15; by = blk >> 4; }
  __shared__ float tile[32][33];
  int k0 = bx * 32, n0 = by * 32;
  int tx = threadIdx.x & 31, ty = threadIdx.x >> 5;
#pragma unroll
  for (int i = 0; i < 4; i++)
    tile[ty + i * 8][tx] = w[(long long)(k0 + ty + i * 8) * N + n0 + tx];
  __syncthreads();
#pragma unroll
  for (int i = 0; i < 4; i++)
    wt[(long long)(n0 + ty + i * 8) * 512 + k0 + tx] = f2bf(tile[tx][ty + i * 8]);
}

// ---------------- GEMM core: C[128x128] = A[M,512] * Wt[N,512]^T ----------------
// m97 structure: single-buffered 32KB LDS, per K-step:
// barrier; stage; vmcnt(0); barrier; compute.

__device__ __forceinline__ void gemm_core(const unsigned short* __restrict__ A,
                                          const unsigned short* __restrict__ Wt,
                                          unsigned short* Al, unsigned short* Bl,
                                          int m0, int n0, f32x4 acc[4][4]) {
  const int lane = threadIdx.x & 63;
  const int wid = threadIdx.x >> 6;
  const int c = lane & 15, g = lane >> 4;
  const int wm = wid >> 1, wn = wid & 1;
  const unsigned short* Ab = A + (long long)m0 * 512;
  const unsigned short* Bb = Wt + (long long)n0 * 512;

  for (int k0 = 0; k0 < 512; k0 += 64) {
    __syncthreads();
#pragma unroll
    for (int i = 0; i < 4; i++) stage8(Ab + k0, 512, Al, wid * 32 + i * 8);
#pragma unroll
    for (int i = 0; i < 4; i++) stage8(Bb + k0, 512, Bl, wid * 32 + i * 8);
    asm volatile("s_waitcnt vmcnt(0)" ::: "memory");
    __syncthreads();
#pragma unroll
    for (int kk = 0; kk < 2; kk++) {
      bf16x8 af[4], bfr[4];
#pragma unroll
      for (int mi = 0; mi < 4; mi++) {
        int row = wm * 64 + mi * 16 + c;
        af[mi] = *(const bf16x8*)&Al[row * 64 + (((kk << 2) | g) ^ swz8(row)) * 8];
      }
#pragma unroll
      for (int ni = 0; ni < 4; ni++) {
        int row = wn * 64 + ni * 16 + c;
        bfr[ni] = *(const bf16x8*)&Bl[row * 64 + (((kk << 2) | g) ^ swz8(row)) * 8];
      }
#pragma unroll
      for (int mi = 0; mi < 4; mi++)
#pragma unroll
        for (int ni = 0; ni < 4; ni++)
          acc[mi][ni] = __builtin_amdgcn_mfma_f32_16x16x32_bf16(af[mi], bfr[ni], acc[mi][ni], 0, 0, 0);
    }
  }
}

__global__ __launch_bounds__(256) void gemm_qkv(const unsigned short* __restrict__ xb,
                                                const unsigned short* __restrict__ wqt,
                                                const float* __restrict__ bqkv,
                                                unsigned short* __restrict__ qb,
                                                unsigned short* __restrict__ kb,
                                                unsigned short* __restrict__ vtb) {
  __shared__ __align__(16) unsigned short Al[128 * 64];
  __shared__ __align__(16) unsigned short Bl[128 * 64];
  f32x4 acc[4][4] = {};
  int m0 = blockIdx.x * 128, n0 = blockIdx.y * 128;
  gemm_core(xb, wqt, Al, Bl, m0, n0, acc);
  const int lane = threadIdx.x & 63;
  const int wid = threadIdx.x >> 6;
  const int c = lane & 15, g = lane >> 4;
  const int wm = wid >> 1, wn = wid & 1;
#pragma unroll
  for (int ni = 0; ni < 4; ni++) {
    int n = n0 + wn * 64 + ni * 16 + c;
    float bv = bqkv[n];
    int which = n >> 9;
    int h = (n & 511) >> 6, d = n & 63;
#pragma unroll
    for (int mi = 0; mi < 4; mi++) {
      int mbase = m0 + wm * 64 + mi * 16 + g * 4;   // 4 consecutive t, same batch
      int b = mbase >> 11, t0 = mbase & 2047;
      int bh = b * 8 + h;
      if (which == 2) {
        // V transposed [bh][d][t]: 4 consecutive t -> one 8B store
        ushort4 o;
        o.x = f2bf(acc[mi][ni][0] + bv); o.y = f2bf(acc[mi][ni][1] + bv);
        o.z = f2bf(acc[mi][ni][2] + bv); o.w = f2bf(acc[mi][ni][3] + bv);
        *(ushort4*)&vtb[((long long)bh * 64 + d) * 2048 + t0] = o;
      } else if (which == 0) {
#pragma unroll
        for (int j = 0; j < 4; j++)
          qb[(bh * 2048 + t0 + j) * 64 + d] = f2bf((acc[mi][ni][j] + bv) * 0.18033688011112042f);
      } else {
#pragma unroll
        for (int j = 0; j < 4; j++)
          kb[(bh * 2048 + t0 + j) * 64 + d] = f2bf(acc[mi][ni][j] + bv);
      }
    }
  }
}

__global__ __launch_bounds__(256) void gemm_proj(const unsigned short* __restrict__ yb,
                                                 const unsigned short* __restrict__ wpt,
                                                 const float* __restrict__ bproj,
                                                 float* __restrict__ out) {
  __shared__ __align__(16) unsigned short Al[128 * 64];
  __shared__ __align__(16) unsigned short Bl[128 * 64];
  f32x4 acc[4][4] = {};
  int m0 = blockIdx.x * 128, n0 = blockIdx.y * 128;
  gemm_core(yb, wpt, Al, Bl, m0, n0, acc);
  const int lane = threadIdx.x & 63;
  const int wid = threadIdx.x >> 6;
  const int c = lane & 15, g = lane >> 4;
  const int wm = wid >> 1, wn = wid & 1;
#pragma unroll
  for (int ni = 0; ni < 4; ni++) {
    int n = n0 + wn * 64 + ni * 16 + c;
    float bv = bproj[n];
#pragma unroll
    for (int mi = 0; mi < 4; mi++) {
      int mbase = m0 + wm * 64 + mi * 16 + g * 4;
#pragma unroll
      for (int j = 0; j < 4; j++)
        out[(long long)(mbase + j) * 512 + n] = acc[mi][ni][j] + bv;
    }
  }
}

// ---------------- flash attention: 4-wave staging, unroll-3 pipeline, counted vmcnt ----
// Grid 512 x 256 thr. bh = bid&31 (XCD-colocated K/V). Tile T <-> buffer T%3 <->
// mask reg m(T%3): compile-time LDS indices, no register rotation (the round-9
// rotation forced a compiler-inserted full-drain waitcnt every tile). Per-lane
// staging source offsets precomputed once; per tile each source advances by a
// constant. 5 VMEM/wave/tile (4 gload16 + 1 mask dwordx2); s_waitcnt vmcnt(5)
// keeps the next tile's group in flight across the barrier. Row-sum denominator
// via ones-A MFMA into lacc (all C rows identical; col = q-row) - no VALU adds,
// no final shuffle.
__global__ __launch_bounds__(256) void attn(const unsigned short* __restrict__ qb,
                                            const unsigned short* __restrict__ kb,
                                            const unsigned short* __restrict__ vtb,
                                            const unsigned long long* __restrict__ mbits,
                                            unsigned short* __restrict__ yb) {
  __shared__ __align__(16) unsigned short Kl[3][64 * 64];
  __shared__ __align__(16) unsigned short Vl[3][64 * 64];
  __shared__ __align__(16) float lut4[16][4];   // nibble -> f32x4 seed (0 / -1e30)
  const int lane = threadIdx.x & 63;
  const int w = threadIdx.x >> 6;          // wave 0..3
  const int l31 = lane & 31, h5 = lane >> 5;
  const int sA = swz8(l31);                // swz8(l31+32) == swz8(l31)
  const int bid = blockIdx.x;
  const int bh = bid & 31;                 // xcd = bid%8 = bh%8 -> K/V L2-resident
  const int q0 = (bid >> 5) * 128;
  const int b = bh >> 3, h = bh & 7;
  const int qglob = q0 + w * 32 + l31;

  if (threadIdx.x < 16) {
    int n = threadIdx.x;
#pragma unroll
    for (int j = 0; j < 4; j++) lut4[n][j] = ((n >> j) & 1) ? 0.0f : -1e30f;
  }
  __syncthreads();

  const unsigned short* qptr = qb + ((long long)bh * 2048 + qglob) * 64;
  bf16x8 qf[4];
#pragma unroll
  for (int cc = 0; cc < 4; cc++) qf[cc] = *(const bf16x8*)(qptr + cc * 16 + h5 * 8);

  const unsigned long long* mrow = mbits + ((long long)b * 2048 + qglob) * 32;

  // per-lane staging sources (constant per-tile increments: K +4096, V +64)
  const int ln8 = lane >> 3, o8 = lane & 7;
  const int rA = w * 16 + ln8, rB = rA + 8;
  const unsigned short* ksA = kb + (long long)bh * 2048 * 64 + rA * 64 + (o8 ^ swz8(rA)) * 8;
  const unsigned short* ksB = kb + (long long)bh * 2048 * 64 + rB * 64 + (o8 ^ swz8(rB)) * 8;
  const unsigned short* vsA = vtb + (long long)bh * 64 * 2048 + (long long)rA * 2048 + (o8 ^ swz8(rA)) * 8;
  const unsigned short* vsB = vtb + (long long)bh * 64 * 2048 + (long long)rB * 2048 + (o8 ^ swz8(rB)) * 8;
  const int ldA = w * 16 * 64, ldB = (w * 16 + 8) * 64;   // wave-uniform LDS dests

  // per-lane fragment column offsets (compile-time per cc after unroll)
  const int uo0 = ((0 + h5) ^ sA) * 8, uo1 = ((2 + h5) ^ sA) * 8;
  const int uo2 = ((4 + h5) ^ sA) * 8, uo3 = ((6 + h5) ^ sA) * 8;

  __bf16 onebf = (__bf16)1.0f;
  bf16x8 ones = {onebf, onebf, onebf, onebf, onebf, onebf, onebf, onebf};

  f32x16 accO0 = {0,0,0,0, 0,0,0,0, 0,0,0,0, 0,0,0,0};
  f32x16 accO1 = {0,0,0,0, 0,0,0,0, 0,0,0,0, 0,0,0,0};
  f32x16 lacc  = {0,0,0,0, 0,0,0,0, 0,0,0,0, 0,0,0,0};

#define STAGE_T(BI) do {                       \
    gload16(ksA, &Kl[BI][0] + ldA);            \
    gload16(ksB, &Kl[BI][0] + ldB);            \
    gload16(vsA, &Vl[BI][0] + ldA);            \
    gload16(vsB, &Vl[BI][0] + ldB);            \
    ksA += 4096; ksB += 4096; vsA += 64; vsB += 64; } while (0)

  auto COMPUTE = [&](const unsigned short* Kb, const unsigned short* Vb,
                     unsigned long long mwv) {
    // seed S^T accumulators from the nibble LUT
    // C reg r of tile ot: kv = ot*32 + (r&3) + 8*(r>>2) + 4*h5
    unsigned lo = (unsigned)mwv, hi = (unsigned)(mwv >> 32);
    f32x16 st0, st1;
#pragma unroll
    for (int j = 0; j < 4; j++) {
      f32x4 s0 = *(const f32x4*)lut4[(lo >> (8 * j + 4 * h5)) & 0xF];
      f32x4 s1 = *(const f32x4*)lut4[(hi >> (8 * j + 4 * h5)) & 0xF];
#pragma unroll
      for (int i = 0; i < 4; i++) { st0[4 * j + i] = s0[i]; st1[4 * j + i] = s1[i]; }
    }
    // S^T = K * Q^T
    __builtin_amdgcn_s_setprio(1);
#pragma unroll
    for (int cc = 0; cc < 4; cc++) {
      const int u = (cc == 0) ? uo0 : (cc == 1) ? uo1 : (cc == 2) ? uo2 : uo3;
      bf16x8 kf0 = *(const bf16x8*)&Kb[l31 * 64 + u];
      bf16x8 kf1 = *(const bf16x8*)&Kb[(32 + l31) * 64 + u];
      st0 = __builtin_amdgcn_mfma_f32_32x32x16_bf16(kf0, qf[cc], st0, 0, 0, 0);
      st1 = __builtin_amdgcn_mfma_f32_32x32x16_bf16(kf1, qf[cc], st1, 0, 0, 0);
    }
    __builtin_amdgcn_s_setprio(0);
    // exp2 softmax (masked entries hit exp2(-1e30) = 0), pack bf16
    unsigned pd[2][8];
#pragma unroll
    for (int m = 0; m < 8; m++) {
      float p0 = exp2fast(st0[2 * m]);
      float p1 = exp2fast(st0[2 * m + 1]);
      float p2 = exp2fast(st1[2 * m]);
      float p3 = exp2fast(st1[2 * m + 1]);
      bf16x2 v0 = {(__bf16)p0, (__bf16)p1};
      bf16x2 v1 = {(__bf16)p2, (__bf16)p3};
      pd[0][m] = __builtin_bit_cast(unsigned, v0);
      pd[1][m] = __builtin_bit_cast(unsigned, v1);
    }
    // PV B-fragments: l <-> l+32 dword exchange
#pragma unroll
    for (int ot = 0; ot < 2; ot++)
#pragma unroll
      for (int hc = 0; hc < 2; hc++) {
        pl32swap(pd[ot][4 * hc + 0], pd[ot][4 * hc + 2]);
        pl32swap(pd[ot][4 * hc + 1], pd[ot][4 * hc + 3]);
      }
    // O^T += V^T * P^T ; row-sum denominator via ones-A MFMA
    __builtin_amdgcn_s_setprio(1);
#pragma unroll
    for (int cc = 0; cc < 4; cc++) {
      u32x4 pu = {pd[cc >> 1][4 * (cc & 1) + 0], pd[cc >> 1][4 * (cc & 1) + 1],
                  pd[cc >> 1][4 * (cc & 1) + 2], pd[cc >> 1][4 * (cc & 1) + 3]};
      bf16x8 pf = __builtin_bit_cast(bf16x8, pu);
      const int u = (cc == 0) ? uo0 : (cc == 1) ? uo1 : (cc == 2) ? uo2 : uo3;
      bf16x8 vf0 = *(const bf16x8*)&Vb[l31 * 64 + u];
      bf16x8 vf1 = *(const bf16x8*)&Vb[(32 + l31) * 64 + u];
      accO0 = __builtin_amdgcn_mfma_f32_32x32x16_bf16(vf0, pf, accO0, 0, 0, 0);
      accO1 = __builtin_amdgcn_mfma_f32_32x32x16_bf16(vf1, pf, accO1, 0, 0, 0);
      lacc  = __builtin_amdgcn_mfma_f32_32x32x16_bf16(ones, pf, lacc, 0, 0, 0);
    }
    __builtin_amdgcn_s_setprio(0);
  };

#define PHASE(TS, BS, BC, MSET, MUSE) do {                 \
    STAGE_T(BS);                                           \
    MSET = mrow[TS];                                       \
    __builtin_amdgcn_sched_barrier(0);                     \
    COMPUTE(&Kl[BC][0], &Vl[BC][0], MUSE);                 \
    asm volatile("s_waitcnt lgkmcnt(0)" ::: "memory");     \
    __builtin_amdgcn_sched_barrier(0);                     \
    asm volatile("s_waitcnt vmcnt(5)" ::: "memory");       \
    __builtin_amdgcn_s_barrier();                          \
    __builtin_amdgcn_sched_barrier(0); } while (0)

  // prologue: tiles 0,1 in flight
  unsigned long long m0, m1, m2;
  __builtin_amdgcn_sched_barrier(0);
  STAGE_T(0); m0 = mrow[0];
  __builtin_amdgcn_sched_barrier(0);
  STAGE_T(1); m1 = mrow[1];
  __builtin_amdgcn_sched_barrier(0);
  asm volatile("s_waitcnt vmcnt(5)" ::: "memory");   // tile-0 group landed
  __builtin_amdgcn_s_barrier();
  __builtin_amdgcn_sched_barrier(0);

  for (int k = 0; k < 10; ++k) {   // tile T: buffer T%3, mask m(T%3)
    PHASE(3 * k + 2, 2, 0, m2, m0);
    PHASE(3 * k + 3, 0, 1, m0, m1);
    PHASE(3 * k + 4, 1, 2, m1, m2);
  }
  // epilogue: tiles 30 (buf0, m0) and 31 (buf1, m1)
  COMPUTE(&Kl[0][0], &Vl[0][0], m0);
  asm volatile("s_waitcnt lgkmcnt(0)" ::: "memory");
  asm volatile("s_waitcnt vmcnt(0)" ::: "memory");   // tile-31 group landed
  __builtin_amdgcn_s_barrier();
  __builtin_amdgcn_sched_barrier(0);
  COMPUTE(&Kl[1][0], &Vl[1][0], m1);

#undef PHASE
#undef STAGE_T

  float linv = 1.0f / lacc[0];   // all lacc rows identical; col = this lane's q-row
  unsigned short* yrow = yb + ((long long)(b * 2048 + qglob)) * 512 + h * 64;
#pragma unroll
  for (int m = 0; m < 4; m++) {
    int d0 = 8 * m + 4 * h5;
    bf16x4 o0 = {(__bf16)(accO0[4 * m + 0] * linv), (__bf16)(accO0[4 * m + 1] * linv),
                 (__bf16)(accO0[4 * m + 2] * linv), (__bf16)(accO0[4 * m + 3] * linv)};
    bf16x4 o1 = {(__bf16)(accO1[4 * m + 0] * linv), (__bf16)(accO1[4 * m + 1] * linv),
                 (__bf16)(accO1[4 * m + 2] * linv), (__bf16)(accO1[4 * m + 3] * linv)};
    *(bf16x4*)&yrow[d0] = o0;
    *(bf16x4*)&yrow[32 + d0] = o1;
  }
}

// ---------------- launcher ----------------

extern "C" void kernel_launch(void* const* d_in, const int* in_sizes, int n_in,
                              void* d_out, int out_size, void* d_ws, size_t ws_size,
                              hipStream_t stream) {
  const float* x      = (const float*)d_in[0];
  const int*   adj    = (const int*)d_in[1];
  const float* w_qkv  = (const float*)d_in[2];
  const float* b_qkv  = (const float*)d_in[3];
  const float* w_proj = (const float*)d_in[4];
  const float* b_proj = (const float*)d_in[5];
  float* out = (float*)d_out;

  char* ws = (char*)d_ws;
  unsigned short* xb  = (unsigned short*)(ws);              // 8.4MB  (reused as yb)
  unsigned short* qb  = (unsigned short*)(ws + 8388608);    // 8.4MB
  unsigned short* kbf = (unsigned short*)(ws + 16777216);   // 8.4MB
  unsigned short* vtb = (unsigned short*)(ws + 25165824);   // 8.4MB
  unsigned short* wqt = (unsigned short*)(ws + 33554432);   // 1.57MB
  unsigned short* wpt = (unsigned short*)(ws + 35127296);   // 0.52MB
  unsigned long long* mb = (unsigned long long*)(ws + 35651584); // 2MB  (end 37.75MB)
  unsigned short* yb = xb;  // x is dead after gemm_qkv

  prep<<<dim3(21504), dim3(256), 0, stream>>>(x, xb, w_qkv, wqt, w_proj, wpt, adj, mb);
  gemm_qkv<<<dim3(64, 12), dim3(256), 0, stream>>>(xb, wqt, b_qkv, qb, kbf, vtb);
  attn<<<dim3(512), dim3(256), 0, stream>>>(qb, kbf, vtb, mb, yb);
  gemm_proj<<<dim3(64, 4), dim3(256), 0, stream>>>(yb, wpt, b_proj, out);
}